// Round 4
// baseline (153.385 us; speedup 1.0000x reference)
//
#include <hip/hip_runtime.h>
#include <stdint.h>

#define B_ 4
#define C_ 128
#define H_ 128
#define W_ 128
#define HW 16384

typedef short short8 __attribute__((ext_vector_type(8)));
typedef float f32x4 __attribute__((ext_vector_type(4)));

__device__ __forceinline__ unsigned pack_bf16(float lo, float hi) {
    unsigned ul = __float_as_uint(lo);
    unsigned uh = __float_as_uint(hi);
    ul = (ul + 0x7fffu + ((ul >> 16) & 1u)) >> 16;
    uh = (uh + 0x7fffu + ((uh >> 16) & 1u)) & 0xffff0000u;
    return uh | ul;
}

__device__ __forceinline__ unsigned cvtpk(float lo, float hi) {
    unsigned r;
    asm("v_cvt_pk_bf16_f32 %0, %1, %2" : "=v"(r) : "v"(lo), "v"(hi));
    return r;
}

__device__ __forceinline__ float u2f_lo(unsigned u) { return __uint_as_float(u << 16); }
__device__ __forceinline__ float u2f_hi(unsigned u) { return __uint_as_float(u & 0xffff0000u); }

__device__ __forceinline__ void gll16(const void* g, void* l) {
    __builtin_amdgcn_global_load_lds((const unsigned int*)g, (unsigned int*)l, 16, 0, 0);
}

// ---------------- prep: weights -> bf16, K reordered to tap*128+c ----------------
__global__ __launch_bounds__(256) void prep_w(const float* __restrict__ w1,
                                              const float* __restrict__ w2,
                                              unsigned short* __restrict__ w1t,
                                              unsigned short* __restrict__ w2t) {
    int i = blockIdx.x * 256 + threadIdx.x;
    const float* src = w1;
    unsigned short* dst = w1t;
    int j = i;
    if (i >= 147456) { j = i - 147456; src = w2; dst = w2t; }
    int o = j / 1152, rem = j % 1152;
    int c = rem / 9, tap = rem % 9;
    unsigned u = __float_as_uint(src[j]);
    u = (u + 0x7fffu + ((u >> 16) & 1u)) >> 16;
    dst[o * 1152 + tap * 128 + c] = (unsigned short)u;
}

__global__ __launch_bounds__(256) void bn_prep(const float* g1, const float* b1, const float* m1, const float* v1,
                                               const float* g2, const float* b2, const float* m2, const float* v2,
                                               float* inv1, float* sh1, float* inv2, float* sh2) {
    int t = threadIdx.x;
    if (t < 128) {
        float iv = g1[t] * rsqrtf(v1[t] + 1e-5f);
        inv1[t] = iv; sh1[t] = b1[t] - m1[t] * iv;
    } else {
        int u = t - 128;
        float iv = g2[u] * rsqrtf(v2[u] + 1e-5f);
        inv2[u] = iv; sh2[u] = b2[u] - m2[u] * iv;
    }
}

// ---------------- x NCHW fp32 -> NHWC bf16 (32x32 tiles) ----------------
__global__ __launch_bounds__(256) void nhwc_k(const float* __restrict__ x,
                                              unsigned short* __restrict__ xh) {
    __shared__ unsigned short tile[32][36];
    int blk = blockIdx.x;
    int wt = blk & 3, ct = (blk >> 2) & 3, h = (blk >> 4) & 127, b = blk >> 11;
    int t = threadIdx.x;
    int c = t >> 3, seg = t & 7;
    const float* srcp = x + ((size_t)((b * 128 + ct * 32 + c) * 128 + h) * 128) + wt * 32 + seg * 4;
    float4 v = *(const float4*)srcp;
    uint2 pk;
    pk.x = pack_bf16(v.x, v.y);
    pk.y = pack_bf16(v.z, v.w);
    *(uint2*)&tile[c][seg * 4] = pk;
    __syncthreads();
    int w = t >> 3, s2 = t & 7;
    unsigned a0 = tile[s2 * 4 + 0][w];
    unsigned a1 = tile[s2 * 4 + 1][w];
    unsigned a2 = tile[s2 * 4 + 2][w];
    unsigned a3 = tile[s2 * 4 + 3][w];
    uint2 o;
    o.x = (a1 << 16) | a0;
    o.y = (a3 << 16) | a2;
    *(uint2*)(xh + ((size_t)((b * 128 + h) * 128 + wt * 32 + w) * 128) + ct * 32 + s2 * 4) = o;
}

// ---------------- zero only the halo border of the intermediate buffer ----------------
__global__ __launch_bounds__(256) void border_k(unsigned short* __restrict__ o1p) {
    int i = blockIdx.x * 256 + threadIdx.x;   // 4 * 516 * 16 = 33024
    if (i >= 33024) return;
    int chunk = i & 15;
    int pos = i >> 4;
    int b = pos / 516;
    int r = pos % 516;
    int row, col;
    if (r < 130)      { row = 0;   col = r; }
    else if (r < 260) { row = 129; col = r - 130; }
    else { int j = r - 260; row = 1 + (j >> 1); col = (j & 1) * 129; }
    uint4 z = {0u, 0u, 0u, 0u};
    *(uint4*)((char*)o1p + (size_t)((b * 130 + row) * 130 + col) * 256 + chunk * 16) = z;
}

#define BLEND(buf, w, dstv) { \
    unsigned* dp_ = (unsigned*)&dstv; \
    _Pragma("unroll") \
    for (int e_ = 0; e_ < 4; ++e_) { \
        unsigned c0_ = ((const unsigned*)&buf[0])[e_]; \
        unsigned c1_ = ((const unsigned*)&buf[1])[e_]; \
        unsigned c2_ = ((const unsigned*)&buf[2])[e_]; \
        unsigned c3_ = ((const unsigned*)&buf[3])[e_]; \
        float lo_ = w[0] * u2f_lo(c0_) + w[1] * u2f_lo(c1_) \
                  + w[2] * u2f_lo(c2_) + w[3] * u2f_lo(c3_); \
        float hi_ = w[0] * u2f_hi(c0_) + w[1] * u2f_hi(c1_) \
                  + w[2] * u2f_hi(c2_) + w[3] * u2f_hi(c3_); \
        dp_[e_] = cvtpk(lo_, hi_); \
    } \
}

// ---------------- GEMM1: fused deformable gather (direct-to-reg) + MFMA + BN1 + ReLU ----------------
__global__ __launch_bounds__(256, 3) void gemm1_k(
    const unsigned short* __restrict__ xh,
    const float* __restrict__ off,
    const unsigned short* __restrict__ w1t,
    const float* __restrict__ inv1,
    const float* __restrict__ sh1,
    unsigned short* __restrict__ out1p) {
    __shared__ __align__(16) char ldsw[32768];   // weight tile [128 o][16 chunks] swizzled

    int bid = blockIdx.x;
    int swz = ((bid & 7) << 6) | (bid >> 3);
    int h = swz & 127, b = swz >> 7;
    int tid = threadIdx.x, lane = tid & 63, wv = tid >> 6;
    int lr = lane & 15, lq = lane >> 4;
    int p0w = wv * 32;
    const uint4* xq = (const uint4*)xh;

    f32x4 acc[8][2] = {};

    for (int tap = 0; tap < 9; ++tap) {
        __syncthreads();   // all waves done reading ldsw of previous tap
        #pragma unroll
        for (int it = 0; it < 8; ++it) {
            int ci = it * 256 + tid;
            int o = ci >> 4, q = ci & 15;
            gll16((const char*)w1t + o * 2304 + tap * 256 + ((q ^ (o & 7)) << 4), ldsw + ci * 16);
        }
        int kh = tap / 3 - 1, kw = tap % 3 - 1;
        int dyB = ((b * 18 + 2 * tap) * H_ + h) * W_;
        int dxB = dyB + HW;

        int pix[2][4];
        float wg[2][4];
        #pragma unroll
        for (int j = 0; j < 2; ++j) {
            int p = p0w + j * 16 + lr;
            float dy = off[dyB + p];
            float dx = off[dxB + p];
            float py = (float)(h + kh) + dy;
            float px = (float)(p + kw) + dx;
            float y0f = floorf(py), x0f = floorf(px);
            int y0 = (int)y0f, x0 = (int)x0f;
            float wy1 = py - y0f, wx1 = px - x0f;
            float wy0 = 1.f - wy1, wx0 = 1.f - wx1;
            int y1 = y0 + 1, x1 = x0 + 1;
            wg[j][0] = ((unsigned)y0 < 128u && (unsigned)x0 < 128u) ? wy0 * wx0 : 0.f;
            wg[j][1] = ((unsigned)y0 < 128u && (unsigned)x1 < 128u) ? wy0 * wx1 : 0.f;
            wg[j][2] = ((unsigned)y1 < 128u && (unsigned)x0 < 128u) ? wy1 * wx0 : 0.f;
            wg[j][3] = ((unsigned)y1 < 128u && (unsigned)x1 < 128u) ? wy1 * wx1 : 0.f;
            int y0c = min(max(y0, 0), 127), y1c = min(max(y1, 0), 127);
            int x0c = min(max(x0, 0), 127), x1c = min(max(x1, 0), 127);
            int r0 = (b * H_ + y0c) * W_, r1 = (b * H_ + y1c) * W_;
            pix[j][0] = r0 + x0c; pix[j][1] = r0 + x1c;
            pix[j][2] = r1 + x0c; pix[j][3] = r1 + x1c;
        }

        uint4 bufA[4], bufB[4];
        #pragma unroll
        for (int k = 0; k < 4; ++k) bufA[k] = xq[(size_t)pix[0][k] * 16 + lq];
        #pragma unroll
        for (int k = 0; k < 4; ++k) bufB[k] = xq[(size_t)pix[1][k] * 16 + lq];

        __syncthreads();   // weight tile staged (barrier drains vmcnt)

        #pragma unroll
        for (int c0s = 0; c0s < 4; ++c0s) {
            short8 bfr0, bfr1;
            BLEND(bufA, wg[0], bfr0);
            if (c0s < 3) {
                #pragma unroll
                for (int k = 0; k < 4; ++k) bufA[k] = xq[(size_t)pix[0][k] * 16 + (c0s + 1) * 4 + lq];
            }
            BLEND(bufB, wg[1], bfr1);
            if (c0s < 3) {
                #pragma unroll
                for (int k = 0; k < 4; ++k) bufB[k] = xq[(size_t)pix[1][k] * 16 + (c0s + 1) * 4 + lq];
            }
            int qn = lq + c0s * 4;
            short8 af[8];
            #pragma unroll
            for (int i = 0; i < 8; ++i) {
                int row = i * 16 + lr;
                af[i] = *(const short8*)(ldsw + row * 256 + ((qn ^ (row & 7)) << 4));
            }
            #pragma unroll
            for (int i = 0; i < 8; ++i) {
                acc[i][0] = __builtin_amdgcn_mfma_f32_16x16x32_bf16(af[i], bfr0, acc[i][0], 0, 0, 0);
                acc[i][1] = __builtin_amdgcn_mfma_f32_16x16x32_bf16(af[i], bfr1, acc[i][1], 0, 0, 0);
            }
        }
    }

    // epilogue: BN1 + ReLU -> bf16, direct NHWC halo store (4 consecutive o per lane)
    #pragma unroll
    for (int i = 0; i < 8; ++i) {
        int o0 = i * 16 + lq * 4;
        float4 iv = *(const float4*)(inv1 + o0);
        float4 sv = *(const float4*)(sh1 + o0);
        #pragma unroll
        for (int j = 0; j < 2; ++j) {
            int p = p0w + j * 16 + lr;
            f32x4 a = acc[i][j];
            float v0 = fmaxf(fmaf(a[0], iv.x, sv.x), 0.f);
            float v1 = fmaxf(fmaf(a[1], iv.y, sv.y), 0.f);
            float v2 = fmaxf(fmaf(a[2], iv.z, sv.z), 0.f);
            float v3 = fmaxf(fmaf(a[3], iv.w, sv.w), 0.f);
            uint2 pk;
            pk.x = cvtpk(v0, v1);
            pk.y = cvtpk(v2, v3);
            size_t idx = (size_t)((b * 130 + h + 1) * 130 + 1 + p) * 128 + o0;
            *(uint2*)(out1p + idx) = pk;
        }
    }
}

// ---------------- GEMM2: dense 3x3 conv, input direct-to-reg + weights LDS ----------------
__global__ __launch_bounds__(256, 3) void gemm2_k(
    const unsigned short* __restrict__ out1p,
    const unsigned short* __restrict__ w2t,
    const float* __restrict__ x,
    const float* __restrict__ inv2,
    const float* __restrict__ sh2,
    float* __restrict__ outp) {
    __shared__ __align__(16) char ldsw[32768];

    int bid = blockIdx.x;
    int swz = ((bid & 7) << 6) | (bid >> 3);
    int h = swz & 127, b = swz >> 7;
    int tid = threadIdx.x, lane = tid & 63, wv = tid >> 6;
    int lr = lane & 15, lq = lane >> 4;
    int p0w = wv * 32;
    const uint4* iq = (const uint4*)out1p;

    f32x4 acc[2][8] = {};

    for (int tap = 0; tap < 9; ++tap) {
        __syncthreads();
        #pragma unroll
        for (int it = 0; it < 8; ++it) {
            int ci = it * 256 + tid;
            int o = ci >> 4, q = ci & 15;
            gll16((const char*)w2t + o * 2304 + tap * 256 + ((q ^ (o & 7)) << 4), ldsw + ci * 16);
        }
        int kh = tap / 3, kw = tap % 3;
        short8 av[2][4];
        #pragma unroll
        for (int j = 0; j < 2; ++j) {
            int p = p0w + j * 16 + lr;
            size_t pixbase = ((size_t)((b * 130 + h + kh) * 130) + p + kw) * 16;
            #pragma unroll
            for (int c0s = 0; c0s < 4; ++c0s)
                av[j][c0s] = *(const short8*)(iq + pixbase + c0s * 4 + lq);
        }
        __syncthreads();
        #pragma unroll
        for (int c0s = 0; c0s < 4; ++c0s) {
            int qn = lq + c0s * 4;
            short8 bw[8];
            #pragma unroll
            for (int i = 0; i < 8; ++i) {
                int row = i * 16 + lr;
                bw[i] = *(const short8*)(ldsw + row * 256 + ((qn ^ (row & 7)) << 4));
            }
            #pragma unroll
            for (int i = 0; i < 8; ++i) {
                acc[0][i] = __builtin_amdgcn_mfma_f32_16x16x32_bf16(av[0][c0s], bw[i], acc[0][i], 0, 0, 0);
                acc[1][i] = __builtin_amdgcn_mfma_f32_16x16x32_bf16(av[1][c0s], bw[i], acc[1][i], 0, 0, 0);
            }
        }
    }

    // epilogue: BN2 + residual + ReLU, coalesced NCHW float4 store
    #pragma unroll
    for (int i = 0; i < 8; ++i) {
        int o = i * 16 + lr;
        float iv = inv2[o], sv = sh2[o];
        #pragma unroll
        for (int j = 0; j < 2; ++j) {
            int p4 = p0w + j * 16 + lq * 4;
            size_t base = ((size_t)(b * C_ + o) * H_ + h) * W_ + p4;
            float4 rx = *(const float4*)(x + base);
            f32x4 a = acc[j][i];
            float4 ov;
            ov.x = fmaxf(fmaf(a[0], iv, sv) + rx.x, 0.f);
            ov.y = fmaxf(fmaf(a[1], iv, sv) + rx.y, 0.f);
            ov.z = fmaxf(fmaf(a[2], iv, sv) + rx.z, 0.f);
            ov.w = fmaxf(fmaf(a[3], iv, sv) + rx.w, 0.f);
            *(float4*)(outp + base) = ov;
        }
    }
}

extern "C" void kernel_launch(void* const* d_in, const int* in_sizes, int n_in,
                              void* d_out, int out_size, void* d_ws, size_t ws_size,
                              hipStream_t stream) {
    const float* x   = (const float*)d_in[0];
    const float* off = (const float*)d_in[1];
    const float* w1  = (const float*)d_in[2];
    const float* g1  = (const float*)d_in[3];
    const float* b1  = (const float*)d_in[4];
    const float* m1  = (const float*)d_in[5];
    const float* v1  = (const float*)d_in[6];
    const float* w2  = (const float*)d_in[7];
    const float* g2  = (const float*)d_in[8];
    const float* b2  = (const float*)d_in[9];
    const float* m2  = (const float*)d_in[10];
    const float* v2  = (const float*)d_in[11];
    float* outp = (float*)d_out;

    char* ws = (char*)d_ws;
    unsigned short* w1t = (unsigned short*)(ws);
    unsigned short* w2t = (unsigned short*)(ws + 294912);
    float* inv1 = (float*)(ws + 589824);
    float* sh1  = (float*)(ws + 590336);
    float* inv2 = (float*)(ws + 590848);
    float* sh2  = (float*)(ws + 591360);
    unsigned short* xh  = (unsigned short*)(ws + 591872);
    unsigned short* o1p = (unsigned short*)(ws + 17369088);

    prep_w<<<1152, 256, 0, stream>>>(w1, w2, w1t, w2t);
    bn_prep<<<1, 256, 0, stream>>>(g1, b1, m1, v1, g2, b2, m2, v2, inv1, sh1, inv2, sh2);
    nhwc_k<<<8192, 256, 0, stream>>>(x, xh);
    border_k<<<129, 256, 0, stream>>>(o1p);
    gemm1_k<<<512, 256, 0, stream>>>(xh, off, w1t, inv1, sh1, o1p);
    gemm2_k<<<512, 256, 0, stream>>>(o1p, w2t, x, inv2, sh2, outp);
}

// Round 5
// 112.438 us; speedup vs baseline: 1.3642x; 1.3642x over previous
//
#include <hip/hip_runtime.h>
#include <stdint.h>

#define B_ 4
#define C_ 128
#define H_ 128
#define W_ 128
#define HW 16384

typedef short short8 __attribute__((ext_vector_type(8)));
typedef float f32x4 __attribute__((ext_vector_type(4)));

__device__ __forceinline__ unsigned pack_bf16(float lo, float hi) {
    unsigned ul = __float_as_uint(lo);
    unsigned uh = __float_as_uint(hi);
    ul = (ul + 0x7fffu + ((ul >> 16) & 1u)) >> 16;
    uh = (uh + 0x7fffu + ((uh >> 16) & 1u)) & 0xffff0000u;
    return uh | ul;
}

__device__ __forceinline__ unsigned cvtpk(float lo, float hi) {
    unsigned r;
    asm("v_cvt_pk_bf16_f32 %0, %1, %2" : "=v"(r) : "v"(lo), "v"(hi));
    return r;
}

__device__ __forceinline__ float u2f_lo(unsigned u) { return __uint_as_float(u << 16); }
__device__ __forceinline__ float u2f_hi(unsigned u) { return __uint_as_float(u & 0xffff0000u); }

__device__ __forceinline__ void gll16(const void* g, void* l) {
    __builtin_amdgcn_global_load_lds((const unsigned int*)g, (unsigned int*)l, 16, 0, 0);
}

// ---------------- prep: weights -> bf16, K reordered to tap*128+c ----------------
__global__ __launch_bounds__(256) void prep_w(const float* __restrict__ w1,
                                              const float* __restrict__ w2,
                                              unsigned short* __restrict__ w1t,
                                              unsigned short* __restrict__ w2t) {
    int i = blockIdx.x * 256 + threadIdx.x;
    const float* src = w1;
    unsigned short* dst = w1t;
    int j = i;
    if (i >= 147456) { j = i - 147456; src = w2; dst = w2t; }
    int o = j / 1152, rem = j % 1152;
    int c = rem / 9, tap = rem % 9;
    unsigned u = __float_as_uint(src[j]);
    u = (u + 0x7fffu + ((u >> 16) & 1u)) >> 16;
    dst[o * 1152 + tap * 128 + c] = (unsigned short)u;
}

__global__ __launch_bounds__(256) void bn_prep(const float* g1, const float* b1, const float* m1, const float* v1,
                                               const float* g2, const float* b2, const float* m2, const float* v2,
                                               float* inv1, float* sh1, float* inv2, float* sh2) {
    int t = threadIdx.x;
    if (t < 128) {
        float iv = g1[t] * rsqrtf(v1[t] + 1e-5f);
        inv1[t] = iv; sh1[t] = b1[t] - m1[t] * iv;
    } else {
        int u = t - 128;
        float iv = g2[u] * rsqrtf(v2[u] + 1e-5f);
        inv2[u] = iv; sh2[u] = b2[u] - m2[u] * iv;
    }
}

// ---------------- x NCHW fp32 -> NHWC bf16 (32x32 tiles) ----------------
__global__ __launch_bounds__(256) void nhwc_k(const float* __restrict__ x,
                                              unsigned short* __restrict__ xh) {
    __shared__ unsigned short tile[32][36];
    int blk = blockIdx.x;
    int wt = blk & 3, ct = (blk >> 2) & 3, h = (blk >> 4) & 127, b = blk >> 11;
    int t = threadIdx.x;
    int c = t >> 3, seg = t & 7;
    const float* srcp = x + ((size_t)((b * 128 + ct * 32 + c) * 128 + h) * 128) + wt * 32 + seg * 4;
    float4 v = *(const float4*)srcp;
    uint2 pk;
    pk.x = pack_bf16(v.x, v.y);
    pk.y = pack_bf16(v.z, v.w);
    *(uint2*)&tile[c][seg * 4] = pk;
    __syncthreads();
    int w = t >> 3, s2 = t & 7;
    unsigned a0 = tile[s2 * 4 + 0][w];
    unsigned a1 = tile[s2 * 4 + 1][w];
    unsigned a2 = tile[s2 * 4 + 2][w];
    unsigned a3 = tile[s2 * 4 + 3][w];
    uint2 o;
    o.x = (a1 << 16) | a0;
    o.y = (a3 << 16) | a2;
    *(uint2*)(xh + ((size_t)((b * 128 + h) * 128 + wt * 32 + w) * 128) + ct * 32 + s2 * 4) = o;
}

// ---------------- zero only the halo border of the intermediate buffer ----------------
__global__ __launch_bounds__(256) void border_k(unsigned short* __restrict__ o1p) {
    int i = blockIdx.x * 256 + threadIdx.x;   // 4 * 516 * 16 = 33024
    if (i >= 33024) return;
    int chunk = i & 15;
    int pos = i >> 4;
    int b = pos / 516;
    int r = pos % 516;
    int row, col;
    if (r < 130)      { row = 0;   col = r; }
    else if (r < 260) { row = 129; col = r - 130; }
    else { int j = r - 260; row = 1 + (j >> 1); col = (j & 1) * 129; }
    uint4 z = {0u, 0u, 0u, 0u};
    *(uint4*)((char*)o1p + (size_t)((b * 130 + row) * 130 + col) * 256 + chunk * 16) = z;
}

// ---------------- GEMM1: fused deformable gather + MFMA + BN1 + ReLU -> halo NHWC bf16 ----------------
// 512 threads, 8 waves, each wave owns [128 o x 16 p] of one (b,h) row.
__global__ __launch_bounds__(512, 4) void gemm1_k(
    const unsigned short* __restrict__ xh,
    const float* __restrict__ off,
    const unsigned short* __restrict__ w1t,
    const float* __restrict__ inv1,
    const float* __restrict__ sh1,
    unsigned short* __restrict__ out1p) {
    __shared__ __align__(16) char ldsw[32768];   // weight tile [128 o][16 chunks] swizzled
    __shared__ __align__(16) char ldsv[32768];   // 8 waves x wave-private [16 p][256B] swizzled

    int bid = blockIdx.x;
    int swz = ((bid & 7) << 6) | (bid >> 3);
    int h = swz & 127, b = swz >> 7;
    int tid = threadIdx.x, lane = tid & 63, wv = tid >> 6;
    int lr = lane & 15, lq = lane >> 4;
    int p0w = wv * 16;
    char* vpriv = ldsv + wv * 4096;
    int grp = lane >> 4;   // position-in-chunk (0..3)
    int seg = lane & 15;   // channel chunk (16B = 8ch)
    int sb = seg * 16;
    int bH = b * H_;
    const char* xb8 = (const char*)xh;

    f32x4 acc[8] = {};

#define COORD(c, P, G) do { \
    int p_ = p0w + (c) * 4 + grp; \
    float dy_ = off[dyB + p_]; \
    float dx_ = off[dxB + p_]; \
    float py_ = (float)(h + kh) + dy_; \
    float px_ = (float)(p_ + kw) + dx_; \
    float y0f_ = floorf(py_), x0f_ = floorf(px_); \
    int y0_ = (int)y0f_, x0_ = (int)x0f_; \
    float wy1_ = py_ - y0f_, wx1_ = px_ - x0f_; \
    float wy0_ = 1.f - wy1_, wx0_ = 1.f - wx1_; \
    int y1_ = y0_ + 1, x1_ = x0_ + 1; \
    G[0] = ((unsigned)y0_ < 128u && (unsigned)x0_ < 128u) ? wy0_ * wx0_ : 0.f; \
    G[1] = ((unsigned)y0_ < 128u && (unsigned)x1_ < 128u) ? wy0_ * wx1_ : 0.f; \
    G[2] = ((unsigned)y1_ < 128u && (unsigned)x0_ < 128u) ? wy1_ * wx0_ : 0.f; \
    G[3] = ((unsigned)y1_ < 128u && (unsigned)x1_ < 128u) ? wy1_ * wx1_ : 0.f; \
    int y0c_ = min(max(y0_, 0), 127), y1c_ = min(max(y1_, 0), 127); \
    int x0c_ = min(max(x0_, 0), 127), x1c_ = min(max(x1_, 0), 127); \
    int r0_ = (bH + y0c_) * W_, r1_ = (bH + y1c_) * W_; \
    P[0] = (unsigned)((r0_ + x0c_) * 256 + sb); \
    P[1] = (unsigned)((r0_ + x1c_) * 256 + sb); \
    P[2] = (unsigned)((r1_ + x0c_) * 256 + sb); \
    P[3] = (unsigned)((r1_ + x1c_) * 256 + sb); \
} while (0)

#define ISSUE(buf, P) do { \
    buf[0] = *(const uint4*)(xb8 + P[0]); \
    buf[1] = *(const uint4*)(xb8 + P[1]); \
    buf[2] = *(const uint4*)(xb8 + P[2]); \
    buf[3] = *(const uint4*)(xb8 + P[3]); \
} while (0)

#define BLEND_STORE(c, buf, G) do { \
    int pl_ = (c) * 4 + grp; \
    uint4 st_; \
    unsigned* so_ = (unsigned*)&st_; \
    _Pragma("unroll") \
    for (int e_ = 0; e_ < 4; ++e_) { \
        unsigned c0_ = ((const unsigned*)&buf[0])[e_]; \
        unsigned c1_ = ((const unsigned*)&buf[1])[e_]; \
        unsigned c2_ = ((const unsigned*)&buf[2])[e_]; \
        unsigned c3_ = ((const unsigned*)&buf[3])[e_]; \
        float lo_ = G[0] * u2f_lo(c0_) + G[1] * u2f_lo(c1_) \
                  + G[2] * u2f_lo(c2_) + G[3] * u2f_lo(c3_); \
        float hi_ = G[0] * u2f_hi(c0_) + G[1] * u2f_hi(c1_) \
                  + G[2] * u2f_hi(c2_) + G[3] * u2f_hi(c3_); \
        so_[e_] = cvtpk(lo_, hi_); \
    } \
    *(uint4*)(vpriv + pl_ * 256 + ((seg ^ (pl_ & 7)) << 4)) = st_; \
} while (0)

    for (int tap = 0; tap < 9; ++tap) {
        __syncthreads();   // all waves done reading ldsw of previous tap
        // stage weight tile for this tap (linear LDS dest, inverse-swizzled source)
        #pragma unroll
        for (int it = 0; it < 4; ++it) {
            int ci = it * 512 + tid;
            int o = ci >> 4, q = ci & 15;
            gll16((const char*)w1t + o * 2304 + tap * 256 + ((q ^ (o & 7)) << 4), ldsw + ci * 16);
        }
        int kh = tap / 3 - 1, kw = tap % 3 - 1;
        int dyB = ((b * 18 + 2 * tap) * H_ + h) * W_;
        int dxB = dyB + HW;

        // gather 16 positions: 4 chunks of 4 p, 2-deep register pipeline
        uint4 bufA[4], bufB[4];
        unsigned PA[4], PB[4];
        float GA[4], GB[4];
        COORD(0, PA, GA); ISSUE(bufA, PA);
        COORD(1, PB, GB); ISSUE(bufB, PB);
        BLEND_STORE(0, bufA, GA);
        COORD(2, PA, GA); ISSUE(bufA, PA);
        BLEND_STORE(1, bufB, GB);
        COORD(3, PB, GB); ISSUE(bufB, PB);
        BLEND_STORE(2, bufA, GA);
        BLEND_STORE(3, bufB, GB);

        __syncthreads();   // weight tile staged (barrier drains vmcnt + lgkm)

        #pragma unroll
        for (int c0s = 0; c0s < 4; ++c0s) {
            int qn = lq + c0s * 4;
            short8 bfr = *(const short8*)(vpriv + lr * 256 + ((qn ^ (lr & 7)) << 4));
            short8 af[8];
            #pragma unroll
            for (int i = 0; i < 8; ++i) {
                int row = i * 16 + lr;
                af[i] = *(const short8*)(ldsw + row * 256 + ((qn ^ (lr & 7)) << 4));
            }
            #pragma unroll
            for (int i = 0; i < 8; ++i)
                acc[i] = __builtin_amdgcn_mfma_f32_16x16x32_bf16(af[i], bfr, acc[i], 0, 0, 0);
        }
    }

#undef COORD
#undef ISSUE
#undef BLEND_STORE

    // epilogue: BN1 + ReLU -> bf16, direct NHWC halo store (4 consecutive o per lane)
    int p = p0w + lr;
    size_t rowbase = (size_t)((b * 130 + h + 1) * 130 + 1 + p) * 128;
    #pragma unroll
    for (int i = 0; i < 8; ++i) {
        int o0 = i * 16 + lq * 4;
        float4 iv = *(const float4*)(inv1 + o0);
        float4 sv = *(const float4*)(sh1 + o0);
        f32x4 a = acc[i];
        float v0 = fmaxf(fmaf(a[0], iv.x, sv.x), 0.f);
        float v1 = fmaxf(fmaf(a[1], iv.y, sv.y), 0.f);
        float v2 = fmaxf(fmaf(a[2], iv.z, sv.z), 0.f);
        float v3 = fmaxf(fmaf(a[3], iv.w, sv.w), 0.f);
        uint2 pk;
        pk.x = cvtpk(v0, v1);
        pk.y = cvtpk(v2, v3);
        *(uint2*)(out1p + rowbase + o0) = pk;
    }
}

// ---------------- GEMM2: dense 3x3 conv from halo NHWC + BN2 + residual + ReLU -> NCHW fp32 ----------------
// 512 threads, 8 waves, each wave owns [16 p x 128 o] of one (b,h) row.
__global__ __launch_bounds__(512, 4) void gemm2_k(
    const unsigned short* __restrict__ out1p,
    const unsigned short* __restrict__ w2t,
    const float* __restrict__ x,
    const float* __restrict__ inv2,
    const float* __restrict__ sh2,
    float* __restrict__ outp) {
    __shared__ __align__(16) char ldsS[33280];   // input row tile [130][16 chunks] swizzled
    __shared__ __align__(16) char ldsw[32768];   // weight tile [128][16 chunks] swizzled

    int bid = blockIdx.x;
    int swz = ((bid & 7) << 6) | (bid >> 3);
    int h = swz & 127, b = swz >> 7;
    int tid = threadIdx.x, lane = tid & 63, wv = tid >> 6;
    int lr = lane & 15, lq = lane >> 4;
    int p0w = wv * 16;

    f32x4 acc[8] = {};

    for (int kh = 0; kh < 3; ++kh) {
        __syncthreads();   // prev-kh readers done before overwriting ldsS
        const char* srow = (const char*)out1p + (size_t)((b * 130 + h + kh) * 130) * 256;
        #pragma unroll
        for (int it = 0; it < 5; ++it) {
            int ci = it * 512 + tid;
            if (ci < 2080) {
                int r = ci >> 4, q = ci & 15;
                gll16(srow + r * 256 + ((q ^ (r & 7)) << 4), ldsS + ci * 16);
            }
        }
        for (int kw = 0; kw < 3; ++kw) {
            int tap = kh * 3 + kw;
            #pragma unroll
            for (int it = 0; it < 4; ++it) {
                int ci = it * 512 + tid;
                int o = ci >> 4, q = ci & 15;
                gll16((const char*)w2t + o * 2304 + tap * 256 + ((q ^ (o & 7)) << 4), ldsw + ci * 16);
            }
            __syncthreads();
            #pragma unroll
            for (int c0s = 0; c0s < 4; ++c0s) {
                int qn = lq + c0s * 4;
                int prow = p0w + lr + kw;
                short8 av = *(const short8*)(ldsS + prow * 256 + ((qn ^ (prow & 7)) << 4));
                short8 bw[8];
                #pragma unroll
                for (int i = 0; i < 8; ++i) {
                    int orow = i * 16 + lr;
                    bw[i] = *(const short8*)(ldsw + orow * 256 + ((qn ^ (lr & 7)) << 4));
                }
                #pragma unroll
                for (int i = 0; i < 8; ++i)
                    acc[i] = __builtin_amdgcn_mfma_f32_16x16x32_bf16(av, bw[i], acc[i], 0, 0, 0);
            }
            if (kw < 2 || kh < 2) __syncthreads();
        }
    }

    // epilogue: BN2 + residual + ReLU, coalesced NCHW float4 store
    int p4 = p0w + lq * 4;
    #pragma unroll
    for (int i = 0; i < 8; ++i) {
        int o = i * 16 + lr;
        float iv = inv2[o], sv = sh2[o];
        size_t base = ((size_t)(b * C_ + o) * H_ + h) * W_ + p4;
        float4 rx = *(const float4*)(x + base);
        f32x4 a = acc[i];
        float4 ov;
        ov.x = fmaxf(fmaf(a[0], iv, sv) + rx.x, 0.f);
        ov.y = fmaxf(fmaf(a[1], iv, sv) + rx.y, 0.f);
        ov.z = fmaxf(fmaf(a[2], iv, sv) + rx.z, 0.f);
        ov.w = fmaxf(fmaf(a[3], iv, sv) + rx.w, 0.f);
        *(float4*)(outp + base) = ov;
    }
}

extern "C" void kernel_launch(void* const* d_in, const int* in_sizes, int n_in,
                              void* d_out, int out_size, void* d_ws, size_t ws_size,
                              hipStream_t stream) {
    const float* x   = (const float*)d_in[0];
    const float* off = (const float*)d_in[1];
    const float* w1  = (const float*)d_in[2];
    const float* g1  = (const float*)d_in[3];
    const float* b1  = (const float*)d_in[4];
    const float* m1  = (const float*)d_in[5];
    const float* v1  = (const float*)d_in[6];
    const float* w2  = (const float*)d_in[7];
    const float* g2  = (const float*)d_in[8];
    const float* b2  = (const float*)d_in[9];
    const float* m2  = (const float*)d_in[10];
    const float* v2  = (const float*)d_in[11];
    float* outp = (float*)d_out;

    char* ws = (char*)d_ws;
    unsigned short* w1t = (unsigned short*)(ws);
    unsigned short* w2t = (unsigned short*)(ws + 294912);
    float* inv1 = (float*)(ws + 589824);
    float* sh1  = (float*)(ws + 590336);
    float* inv2 = (float*)(ws + 590848);
    float* sh2  = (float*)(ws + 591360);
    unsigned short* xh  = (unsigned short*)(ws + 591872);
    unsigned short* o1p = (unsigned short*)(ws + 17369088);

    prep_w<<<1152, 256, 0, stream>>>(w1, w2, w1t, w2t);
    bn_prep<<<1, 256, 0, stream>>>(g1, b1, m1, v1, g2, b2, m2, v2, inv1, sh1, inv2, sh2);
    nhwc_k<<<8192, 256, 0, stream>>>(x, xh);
    border_k<<<129, 256, 0, stream>>>(o1p);
    gemm1_k<<<512, 512, 0, stream>>>(xh, off, w1t, inv1, sh1, o1p);
    gemm2_k<<<512, 512, 0, stream>>>(o1p, w2t, x, inv2, sh2, outp);
}